// Round 1
// baseline (572.404 us; speedup 1.0000x reference)
//
#include <hip/hip_runtime.h>
#include <cstddef>

#define N_NODES 50000
#define N_EDGES 1600000
#define N_ETOT  (N_EDGES + N_NODES)
#define F_IN    512
#define HEADS   8
#define HID     8
#define CLS     16

typedef float v4 __attribute__((ext_vector_type(4)));

// ---------------- GEMM1: x(50000x512) @ W1(512x64) -> h1(50000x64) -------------
__global__ __launch_bounds__(256) void gemm1_kernel(
    const float* __restrict__ x, const float* __restrict__ W,
    float* __restrict__ h1, int nrows) {
  __shared__ float xs[64][36];   // [m][k], pad row to 36 floats (144B, 16B-aligned)
  __shared__ float ws[32][68];   // [k][n], pad row to 68 floats (272B, 16B-aligned)
  int t  = threadIdx.x;
  int tx = t & 15, ty = t >> 4;
  int row0 = blockIdx.x * 64;
  v4 acc[4];
  acc[0] = 0.f; acc[1] = 0.f; acc[2] = 0.f; acc[3] = 0.f;

  for (int k0 = 0; k0 < F_IN; k0 += 32) {
    // load x tile: 64 rows x 32 k = 512 float4 -> 2 per thread
#pragma unroll
    for (int r = 0; r < 2; ++r) {
      int idx = t + r * 256;
      int m = idx >> 3;
      int kk = (idx & 7) * 4;
      v4 v = 0.f;
      int grow = row0 + m;
      if (grow < nrows) v = *(const v4*)(x + (size_t)grow * F_IN + k0 + kk);
      *(v4*)&xs[m][kk] = v;
    }
    // load W tile: 32 k x 64 n = 512 float4 -> 2 per thread
#pragma unroll
    for (int r = 0; r < 2; ++r) {
      int idx = t + r * 256;
      int kk = idx >> 4;
      int nn = (idx & 15) * 4;
      *(v4*)&ws[kk][nn] = *(const v4*)(W + (size_t)(k0 + kk) * 64 + nn);
    }
    __syncthreads();
#pragma unroll
    for (int kk = 0; kk < 32; kk += 4) {
      v4 a[4], b[4];
#pragma unroll
      for (int i = 0; i < 4; ++i) a[i] = *(const v4*)&xs[ty * 4 + i][kk];
#pragma unroll
      for (int tt = 0; tt < 4; ++tt) b[tt] = *(const v4*)&ws[kk + tt][tx * 4];
#pragma unroll
      for (int i = 0; i < 4; ++i) {
        acc[i] += a[i][0] * b[0];
        acc[i] += a[i][1] * b[1];
        acc[i] += a[i][2] * b[2];
        acc[i] += a[i][3] * b[3];
      }
    }
    __syncthreads();
  }
#pragma unroll
  for (int i = 0; i < 4; ++i) {
    int grow = row0 + ty * 4 + i;
    if (grow < nrows)
      *(v4*)(h1 + (size_t)grow * 64 + tx * 4) = acc[i];
  }
}

// ------------- per-node attention logits for layer 1: [n,8] each ---------------
__global__ __launch_bounds__(256) void attn1_kernel(
    const float* __restrict__ h1, const float* __restrict__ att_src,
    const float* __restrict__ att_dst, float* __restrict__ a_src,
    float* __restrict__ a_dst, int n) {
  int i = blockIdx.x * 256 + threadIdx.x;   // over n*8 (node,head)
  if (i >= n * HEADS) return;
  int h = i & 7;
  v4 h0 = *(const v4*)(h1 + (size_t)i * 8);
  v4 h1v = *(const v4*)(h1 + (size_t)i * 8 + 4);
  v4 s0 = *(const v4*)(att_src + h * 8);
  v4 s1 = *(const v4*)(att_src + h * 8 + 4);
  v4 d0 = *(const v4*)(att_dst + h * 8);
  v4 d1 = *(const v4*)(att_dst + h * 8 + 4);
  v4 ps = h0 * s0 + h1v * s1;
  v4 pd = h0 * d0 + h1v * d1;
  a_src[i] = ps[0] + ps[1] + ps[2] + ps[3];
  a_dst[i] = pd[0] + pd[1] + pd[2] + pd[3];
}

// --------------------------- CSR build ----------------------------------------
__global__ __launch_bounds__(256) void hist_kernel(
    const int* __restrict__ dst_idx, int* __restrict__ counts) {
  int e = blockIdx.x * 256 + threadIdx.x;
  if (e >= N_ETOT) return;
  int d = (e < N_EDGES) ? dst_idx[e] : (e - N_EDGES);
  atomicAdd(&counts[d], 1);
}

__global__ __launch_bounds__(256) void scan_block_kernel(
    const int* __restrict__ counts, int* __restrict__ indptr,
    int* __restrict__ blocksums, int n) {
  __shared__ int sm[256];
  int t = threadIdx.x;
  int i = blockIdx.x * 256 + t;
  int v = (i < n) ? counts[i] : 0;
  sm[t] = v;
  __syncthreads();
  for (int o = 1; o < 256; o <<= 1) {
    int u = (t >= o) ? sm[t - o] : 0;
    __syncthreads();
    sm[t] += u;
    __syncthreads();
  }
  if (i < n) indptr[i] = sm[t] - v;   // exclusive within block
  if (t == 255) blocksums[blockIdx.x] = sm[255];
}

__global__ __launch_bounds__(256) void scan_top_kernel(int* __restrict__ bs, int nb) {
  __shared__ int sm[256];
  int t = threadIdx.x;
  int v = (t < nb) ? bs[t] : 0;
  sm[t] = v;
  __syncthreads();
  for (int o = 1; o < 256; o <<= 1) {
    int u = (t >= o) ? sm[t - o] : 0;
    __syncthreads();
    sm[t] += u;
    __syncthreads();
  }
  bs[t] = sm[t] - v;   // exclusive
}

__global__ __launch_bounds__(256) void scan_add_kernel(
    int* __restrict__ indptr, const int* __restrict__ bs, int n, int total) {
  int i = blockIdx.x * 256 + threadIdx.x;
  if (i < n) indptr[i] += bs[blockIdx.x];
  if (i == 0) indptr[n] = total;
}

__global__ __launch_bounds__(256) void scatter_kernel(
    const int* __restrict__ src_idx, const int* __restrict__ dst_idx,
    const int* __restrict__ indptr, int* __restrict__ cursor,
    int* __restrict__ csr_src) {
  int e = blockIdx.x * 256 + threadIdx.x;
  if (e >= N_ETOT) return;
  int s, d;
  if (e < N_EDGES) { s = src_idx[e]; d = dst_idx[e]; }
  else             { s = d = e - N_EDGES; }
  int pos = indptr[d] + atomicAdd(&cursor[d], 1);
  csr_src[pos] = s;
}

// ------------- layer-1 edge softmax + aggregate: one wave per node -------------
__global__ __launch_bounds__(256) void agg1_kernel(
    const int* __restrict__ indptr, const int* __restrict__ csr_src,
    const float* __restrict__ h1, const float* __restrict__ a_src1,
    const float* __restrict__ a_dst1, const float* __restrict__ bias1,
    float* __restrict__ h_elu, int n) {
  int wave = threadIdx.x >> 6;
  int lane = threadIdx.x & 63;
  int node = blockIdx.x * 4 + wave;
  if (node >= n) return;
  int h = lane >> 3;
  float adst = a_dst1[node * 8 + h];
  int beg = indptr[node], end = indptr[node + 1];
  float acc = 0.f, den = 0.f;
  for (int i = beg; i < end; ++i) {
    int s = csr_src[i];
    float e = a_src1[s * 8 + h] + adst;
    e = (e > 0.f) ? e : 0.2f * e;      // leaky_relu
    float w = __expf(e);
    den += w;
    acc += w * h1[(size_t)s * 64 + lane];
  }
  float o = acc / den + bias1[lane];
  o = (o > 0.f) ? o : expm1f(o);       // elu
  h_elu[(size_t)node * 64 + lane] = o;
}

// --------- GEMM2: h_elu(50000x64) @ W2(64x16) + attn2 logits epilogue ----------
__global__ __launch_bounds__(256) void gemm2_kernel(
    const float* __restrict__ h_elu, const float* __restrict__ W2,
    const float* __restrict__ att_src2, const float* __restrict__ att_dst2,
    float* __restrict__ h2, float* __restrict__ a_src2,
    float* __restrict__ a_dst2, int n) {
  __shared__ float xs[64][68];
  __shared__ float ws[64][16];
  int t = threadIdx.x;
  int row0 = blockIdx.x * 64;
  // load W2 (64x16): 1 float4 per thread
  {
    int k = t >> 2, c4 = (t & 3) * 4;
    *(v4*)&ws[k][c4] = *(const v4*)(W2 + (size_t)k * 16 + c4);
  }
  // load tile 64x64: 4 float4 per thread
#pragma unroll
  for (int r = 0; r < 4; ++r) {
    int idx = t + r * 256;
    int m = idx >> 4;
    int c4 = (idx & 15) * 4;
    v4 v = 0.f;
    int grow = row0 + m;
    if (grow < n) v = *(const v4*)(h_elu + (size_t)grow * 64 + c4);
    *(v4*)&xs[m][c4] = v;
  }
  __syncthreads();
  int r = t >> 2, q = t & 3;
  int grow = row0 + r;
  v4 acc = 0.f;
#pragma unroll
  for (int k = 0; k < 64; ++k) {
    acc += xs[r][k] * *(const v4*)&ws[k][q * 4];
  }
  v4 asv = *(const v4*)(att_src2 + q * 4);
  v4 adv = *(const v4*)(att_dst2 + q * 4);
  float ps = acc[0] * asv[0] + acc[1] * asv[1] + acc[2] * asv[2] + acc[3] * asv[3];
  float pd = acc[0] * adv[0] + acc[1] * adv[1] + acc[2] * adv[2] + acc[3] * adv[3];
  ps += __shfl_xor(ps, 1); ps += __shfl_xor(ps, 2);
  pd += __shfl_xor(pd, 1); pd += __shfl_xor(pd, 2);
  if (grow < n) {
    *(v4*)(h2 + (size_t)grow * 16 + q * 4) = acc;
    if (q == 0) { a_src2[grow] = ps; a_dst2[grow] = pd; }
  }
}

// ------- layer-2 aggregate + bias + log_softmax: one wave per node -------------
__global__ __launch_bounds__(256) void agg2_kernel(
    const int* __restrict__ indptr, const int* __restrict__ csr_src,
    const float* __restrict__ h2, const float* __restrict__ a_src2,
    const float* __restrict__ a_dst2, const float* __restrict__ bias2,
    float* __restrict__ out, int n) {
  int wave = threadIdx.x >> 6;
  int lane = threadIdx.x & 63;
  int node = blockIdx.x * 4 + wave;
  if (node >= n) return;
  int j = lane >> 4, c = lane & 15;
  float adst = a_dst2[node];
  int beg = indptr[node], end = indptr[node + 1];
  float acc = 0.f, den = 0.f;
  for (int i = beg + j; i < end; i += 4) {
    int s = csr_src[i];
    float e = a_src2[s] + adst;
    e = (e > 0.f) ? e : 0.2f * e;
    float w = __expf(e);
    den += w;
    acc += w * h2[(size_t)s * 16 + c];
  }
  acc += __shfl_xor(acc, 16); acc += __shfl_xor(acc, 32);
  den += __shfl_xor(den, 16); den += __shfl_xor(den, 32);
  float val = acc / den + bias2[c];
  // log_softmax over the 16 classes (lanes 0..15 within each 16-group)
  float m = val;
  for (int o = 1; o < 16; o <<= 1) m = fmaxf(m, __shfl_xor(m, o));
  float ex = __expf(val - m);
  float ssum = ex;
  for (int o = 1; o < 16; o <<= 1) ssum += __shfl_xor(ssum, o);
  float res = val - m - __logf(ssum);
  if (lane < 16) out[(size_t)node * 16 + c] = res;
}

// ------------------------------------------------------------------------------
extern "C" void kernel_launch(void* const* d_in, const int* in_sizes, int n_in,
                              void* d_out, int out_size, void* d_ws, size_t ws_size,
                              hipStream_t stream) {
  const float* x        = (const float*)d_in[0];
  const int*   ei       = (const int*)d_in[1];
  const float* W1       = (const float*)d_in[2];
  const float* att_src1 = (const float*)d_in[3];
  const float* att_dst1 = (const float*)d_in[4];
  const float* bias1    = (const float*)d_in[5];
  const float* W2       = (const float*)d_in[6];
  const float* att_src2 = (const float*)d_in[7];
  const float* att_dst2 = (const float*)d_in[8];
  const float* bias2    = (const float*)d_in[9];
  const int* src_idx = ei;
  const int* dst_idx = ei + N_EDGES;

  char* p = (char*)d_ws;
  auto alloc = [&](size_t bytes) {
    void* r = (void*)p;
    p += (bytes + 255) & ~(size_t)255;
    return r;
  };
  float* h1      = (float*)alloc((size_t)N_NODES * 64 * 4);
  float* h_elu   = (float*)alloc((size_t)N_NODES * 64 * 4);
  float* a_src1  = (float*)alloc((size_t)N_NODES * 8 * 4);
  float* a_dst1  = (float*)alloc((size_t)N_NODES * 8 * 4);
  float* h2      = (float*)alloc((size_t)N_NODES * 16 * 4);
  float* a_src2  = (float*)alloc((size_t)N_NODES * 4);
  float* a_dst2  = (float*)alloc((size_t)N_NODES * 4);
  int* counts    = (int*)alloc((size_t)N_NODES * 4);
  int* cursor    = (int*)alloc((size_t)N_NODES * 4);
  int* indptr    = (int*)alloc((size_t)(N_NODES + 1) * 4);
  int* blocksums = (int*)alloc(256 * 4);
  int* csr_src   = (int*)alloc((size_t)N_ETOT * 4);

  hipMemsetAsync(counts, 0, (size_t)N_NODES * 4, stream);
  hipMemsetAsync(cursor, 0, (size_t)N_NODES * 4, stream);

  gemm1_kernel<<<(N_NODES + 63) / 64, 256, 0, stream>>>(x, W1, h1, N_NODES);
  attn1_kernel<<<(N_NODES * 8 + 255) / 256, 256, 0, stream>>>(
      h1, att_src1, att_dst1, a_src1, a_dst1, N_NODES);

  hist_kernel<<<(N_ETOT + 255) / 256, 256, 0, stream>>>(dst_idx, counts);
  int nb = (N_NODES + 255) / 256;  // 196
  scan_block_kernel<<<nb, 256, 0, stream>>>(counts, indptr, blocksums, N_NODES);
  scan_top_kernel<<<1, 256, 0, stream>>>(blocksums, nb);
  scan_add_kernel<<<nb, 256, 0, stream>>>(indptr, blocksums, N_NODES, N_ETOT);
  scatter_kernel<<<(N_ETOT + 255) / 256, 256, 0, stream>>>(
      src_idx, dst_idx, indptr, cursor, csr_src);

  agg1_kernel<<<N_NODES / 4, 256, 0, stream>>>(
      indptr, csr_src, h1, a_src1, a_dst1, bias1, h_elu, N_NODES);

  gemm2_kernel<<<(N_NODES + 63) / 64, 256, 0, stream>>>(
      h_elu, W2, att_src2, att_dst2, h2, a_src2, a_dst2, N_NODES);

  agg2_kernel<<<N_NODES / 4, 256, 0, stream>>>(
      indptr, csr_src, h2, a_src2, a_dst2, bias2, (float*)d_out, N_NODES);
}

// Round 2
// 499.219 us; speedup vs baseline: 1.1466x; 1.1466x over previous
//
#include <hip/hip_runtime.h>
#include <cstddef>

#define N_NODES 50000
#define N_EDGES 1600000
#define N_ETOT  (N_EDGES + N_NODES)
#define F_IN    512
#define HEADS   8
#define HID     8
#define CLS     16

typedef float v4 __attribute__((ext_vector_type(4)));
typedef unsigned short us4 __attribute__((ext_vector_type(4)));

__device__ inline float b2f(unsigned short u) {
  union { float f; unsigned int i; } v;
  v.i = ((unsigned int)u) << 16;
  return v.f;
}
__device__ inline unsigned short f2b(float f) {
  unsigned int x = __float_as_uint(f);
  unsigned int r = (x + 0x7fffu + ((x >> 16) & 1u)) >> 16;   // RNE
  return (unsigned short)r;
}

// ---- GEMM1: x(50000x512) @ W1(512x64) -> h1b(bf16) + attn logits epilogue ----
__global__ __launch_bounds__(256) void gemm1_kernel(
    const float* __restrict__ x, const float* __restrict__ W,
    const float* __restrict__ att_src, const float* __restrict__ att_dst,
    unsigned short* __restrict__ h1b, float* __restrict__ a_src,
    float* __restrict__ a_dst, int nrows) {
  __shared__ float xs[64][36];
  __shared__ float ws[32][68];
  int t  = threadIdx.x;
  int tx = t & 15, ty = t >> 4;
  int row0 = blockIdx.x * 64;
  v4 acc[4];
  acc[0] = 0.f; acc[1] = 0.f; acc[2] = 0.f; acc[3] = 0.f;

  for (int k0 = 0; k0 < F_IN; k0 += 32) {
#pragma unroll
    for (int r = 0; r < 2; ++r) {
      int idx = t + r * 256;
      int m = idx >> 3;
      int kk = (idx & 7) * 4;
      v4 v = 0.f;
      int grow = row0 + m;
      if (grow < nrows) v = *(const v4*)(x + (size_t)grow * F_IN + k0 + kk);
      *(v4*)&xs[m][kk] = v;
    }
#pragma unroll
    for (int r = 0; r < 2; ++r) {
      int idx = t + r * 256;
      int kk = idx >> 4;
      int nn = (idx & 15) * 4;
      *(v4*)&ws[kk][nn] = *(const v4*)(W + (size_t)(k0 + kk) * 64 + nn);
    }
    __syncthreads();
#pragma unroll
    for (int kk = 0; kk < 32; kk += 4) {
      v4 a[4], b[4];
#pragma unroll
      for (int i = 0; i < 4; ++i) a[i] = *(const v4*)&xs[ty * 4 + i][kk];
#pragma unroll
      for (int tt = 0; tt < 4; ++tt) b[tt] = *(const v4*)&ws[kk + tt][tx * 4];
#pragma unroll
      for (int i = 0; i < 4; ++i) {
        acc[i] += a[i][0] * b[0];
        acc[i] += a[i][1] * b[1];
        acc[i] += a[i][2] * b[2];
        acc[i] += a[i][3] * b[3];
      }
    }
    __syncthreads();
  }
  // epilogue: bf16 store + per-node attention logits (exact, from fp32 acc)
  v4 avs = *(const v4*)(att_src + tx * 4);   // att flat [64]; cols tx*4..+3 in head tx>>1
  v4 avd = *(const v4*)(att_dst + tx * 4);
#pragma unroll
  for (int i = 0; i < 4; ++i) {
    int grow = row0 + ty * 4 + i;
    float ps = acc[i][0]*avs[0] + acc[i][1]*avs[1] + acc[i][2]*avs[2] + acc[i][3]*avs[3];
    float pd = acc[i][0]*avd[0] + acc[i][1]*avd[1] + acc[i][2]*avd[2] + acc[i][3]*avd[3];
    ps += __shfl_xor(ps, 1);
    pd += __shfl_xor(pd, 1);
    if (grow < nrows) {
      us4 o;
      o.x = f2b(acc[i][0]); o.y = f2b(acc[i][1]);
      o.z = f2b(acc[i][2]); o.w = f2b(acc[i][3]);
      *(us4*)(h1b + (size_t)grow * 64 + tx * 4) = o;
      if (!(tx & 1)) {
        int head = tx >> 1;
        a_src[grow * 8 + head] = ps;
        a_dst[grow * 8 + head] = pd;
      }
    }
  }
}

// --------------------------- CSR build ----------------------------------------
__global__ __launch_bounds__(256) void hist_kernel(
    const int* __restrict__ dst_idx, int* __restrict__ counts) {
  int e = blockIdx.x * 256 + threadIdx.x;
  if (e >= N_ETOT) return;
  int d = (e < N_EDGES) ? dst_idx[e] : (e - N_EDGES);
  atomicAdd(&counts[d], 1);
}

__global__ __launch_bounds__(256) void scan_block_kernel(
    const int* __restrict__ counts, int* __restrict__ indptr,
    int* __restrict__ blocksums, int n) {
  __shared__ int sm[256];
  int t = threadIdx.x;
  int i = blockIdx.x * 256 + t;
  int v = (i < n) ? counts[i] : 0;
  sm[t] = v;
  __syncthreads();
  for (int o = 1; o < 256; o <<= 1) {
    int u = (t >= o) ? sm[t - o] : 0;
    __syncthreads();
    sm[t] += u;
    __syncthreads();
  }
  if (i < n) indptr[i] = sm[t] - v;
  if (t == 255) blocksums[blockIdx.x] = sm[255];
}

__global__ __launch_bounds__(256) void scan_top_kernel(int* __restrict__ bs, int nb) {
  __shared__ int sm[256];
  int t = threadIdx.x;
  int v = (t < nb) ? bs[t] : 0;
  sm[t] = v;
  __syncthreads();
  for (int o = 1; o < 256; o <<= 1) {
    int u = (t >= o) ? sm[t - o] : 0;
    __syncthreads();
    sm[t] += u;
    __syncthreads();
  }
  bs[t] = sm[t] - v;
}

__global__ __launch_bounds__(256) void scan_add_kernel(
    int* __restrict__ indptr, const int* __restrict__ bs, int n, int total) {
  int i = blockIdx.x * 256 + threadIdx.x;
  if (i < n) indptr[i] += bs[blockIdx.x];
  if (i == 0) indptr[n] = total;
}

__global__ __launch_bounds__(256) void scatter_kernel(
    const int* __restrict__ src_idx, const int* __restrict__ dst_idx,
    const int* __restrict__ indptr, int* __restrict__ cursor,
    int* __restrict__ csr_src) {
  int e = blockIdx.x * 256 + threadIdx.x;
  if (e >= N_ETOT) return;
  int s, d;
  if (e < N_EDGES) { s = src_idx[e]; d = dst_idx[e]; }
  else             { s = d = e - N_EDGES; }
  int pos = indptr[d] + atomicAdd(&cursor[d], 1);
  csr_src[pos] = s;
}

// ------------- layer-1 edge softmax + aggregate: one wave per node -------------
// cooperative csr_src load + shfl broadcast; bf16 feature gather
__global__ __launch_bounds__(256) void agg1_kernel(
    const int* __restrict__ indptr, const int* __restrict__ csr_src,
    const unsigned short* __restrict__ h1b, const float* __restrict__ a_src1,
    const float* __restrict__ a_dst1, const float* __restrict__ bias1,
    float* __restrict__ h_elu, int n) {
  int wave = threadIdx.x >> 6;
  int lane = threadIdx.x & 63;
  int node = blockIdx.x * 4 + wave;
  if (node >= n) return;
  int h = lane >> 3;
  float adst = a_dst1[node * 8 + h];
  int beg = indptr[node], end = indptr[node + 1];
  float acc = 0.f, den = 0.f;
  for (int base = beg; base < end; base += 64) {
    int m = end - base;
    if (m > 64) m = 64;
    int sv = (lane < m) ? csr_src[base + lane] : 0;
#pragma unroll 2
    for (int j = 0; j < m; ++j) {
      int s = __shfl(sv, j);
      float e = a_src1[s * 8 + h] + adst;
      e = (e > 0.f) ? e : 0.2f * e;
      float w = __expf(e);
      den += w;
      acc += w * b2f(h1b[(size_t)s * 64 + lane]);
    }
  }
  float o = acc / den + bias1[lane];
  o = (o > 0.f) ? o : expm1f(o);
  h_elu[(size_t)node * 64 + lane] = o;
}

// --------- GEMM2: h_elu(50000x64) @ W2(64x16) + attn2 logits epilogue ----------
__global__ __launch_bounds__(256) void gemm2_kernel(
    const float* __restrict__ h_elu, const float* __restrict__ W2,
    const float* __restrict__ att_src2, const float* __restrict__ att_dst2,
    unsigned short* __restrict__ h2b, float* __restrict__ a_src2,
    float* __restrict__ a_dst2, int n) {
  __shared__ float xs[64][68];
  __shared__ float ws[64][16];
  int t = threadIdx.x;
  int row0 = blockIdx.x * 64;
  {
    int k = t >> 2, c4 = (t & 3) * 4;
    *(v4*)&ws[k][c4] = *(const v4*)(W2 + (size_t)k * 16 + c4);
  }
#pragma unroll
  for (int r = 0; r < 4; ++r) {
    int idx = t + r * 256;
    int m = idx >> 4;
    int c4 = (idx & 15) * 4;
    v4 v = 0.f;
    int grow = row0 + m;
    if (grow < n) v = *(const v4*)(h_elu + (size_t)grow * 64 + c4);
    *(v4*)&xs[m][c4] = v;
  }
  __syncthreads();
  int r = t >> 2, q = t & 3;
  int grow = row0 + r;
  v4 acc = 0.f;
#pragma unroll
  for (int k = 0; k < 64; ++k) {
    acc += xs[r][k] * *(const v4*)&ws[k][q * 4];
  }
  v4 asv = *(const v4*)(att_src2 + q * 4);
  v4 adv = *(const v4*)(att_dst2 + q * 4);
  float ps = acc[0] * asv[0] + acc[1] * asv[1] + acc[2] * asv[2] + acc[3] * asv[3];
  float pd = acc[0] * adv[0] + acc[1] * adv[1] + acc[2] * adv[2] + acc[3] * adv[3];
  ps += __shfl_xor(ps, 1); ps += __shfl_xor(ps, 2);
  pd += __shfl_xor(pd, 1); pd += __shfl_xor(pd, 2);
  if (grow < n) {
    us4 o;
    o.x = f2b(acc[0]); o.y = f2b(acc[1]); o.z = f2b(acc[2]); o.w = f2b(acc[3]);
    *(us4*)(h2b + (size_t)grow * 16 + q * 4) = o;
    if (q == 0) { a_src2[grow] = ps; a_dst2[grow] = pd; }
  }
}

// ------- layer-2 aggregate + bias + log_softmax: one wave per node -------------
__global__ __launch_bounds__(256) void agg2_kernel(
    const int* __restrict__ indptr, const int* __restrict__ csr_src,
    const unsigned short* __restrict__ h2b, const float* __restrict__ a_src2,
    const float* __restrict__ a_dst2, const float* __restrict__ bias2,
    float* __restrict__ out, int n) {
  int wave = threadIdx.x >> 6;
  int lane = threadIdx.x & 63;
  int node = blockIdx.x * 4 + wave;
  if (node >= n) return;
  int g = lane >> 4, c = lane & 15;
  float adst = a_dst2[node];
  int beg = indptr[node], end = indptr[node + 1];
  float acc = 0.f, den = 0.f;
  for (int base = beg; base < end; base += 64) {
    int m = end - base;
    if (m > 64) m = 64;
    int sv = (lane < m) ? csr_src[base + lane] : 0;
    for (int j4 = 0; j4 < m; j4 += 4) {
      int idx = j4 + g;
      if (idx < m) {
        int s = __shfl(sv, idx);
        float e = a_src2[s] + adst;
        e = (e > 0.f) ? e : 0.2f * e;
        float w = __expf(e);
        den += w;
        acc += w * b2f(h2b[(size_t)s * 16 + c]);
      }
    }
  }
  acc += __shfl_xor(acc, 16); acc += __shfl_xor(acc, 32);
  den += __shfl_xor(den, 16); den += __shfl_xor(den, 32);
  float val = acc / den + bias2[c];
  float mx = val;
  for (int o = 1; o < 16; o <<= 1) mx = fmaxf(mx, __shfl_xor(mx, o));
  float ex = __expf(val - mx);
  float ssum = ex;
  for (int o = 1; o < 16; o <<= 1) ssum += __shfl_xor(ssum, o);
  float res = val - mx - __logf(ssum);
  if (lane < 16) out[(size_t)node * 16 + c] = res;
}

// ------------------------------------------------------------------------------
extern "C" void kernel_launch(void* const* d_in, const int* in_sizes, int n_in,
                              void* d_out, int out_size, void* d_ws, size_t ws_size,
                              hipStream_t stream) {
  const float* x        = (const float*)d_in[0];
  const int*   ei       = (const int*)d_in[1];
  const float* W1       = (const float*)d_in[2];
  const float* att_src1 = (const float*)d_in[3];
  const float* att_dst1 = (const float*)d_in[4];
  const float* bias1    = (const float*)d_in[5];
  const float* W2       = (const float*)d_in[6];
  const float* att_src2 = (const float*)d_in[7];
  const float* att_dst2 = (const float*)d_in[8];
  const float* bias2    = (const float*)d_in[9];
  const int* src_idx = ei;
  const int* dst_idx = ei + N_EDGES;

  char* p = (char*)d_ws;
  auto alloc = [&](size_t bytes) {
    void* r = (void*)p;
    p += (bytes + 255) & ~(size_t)255;
    return r;
  };
  unsigned short* h1b = (unsigned short*)alloc((size_t)N_NODES * 64 * 2);
  float* h_elu   = (float*)alloc((size_t)N_NODES * 64 * 4);
  float* a_src1  = (float*)alloc((size_t)N_NODES * 8 * 4);
  float* a_dst1  = (float*)alloc((size_t)N_NODES * 8 * 4);
  unsigned short* h2b = (unsigned short*)alloc((size_t)N_NODES * 16 * 2);
  float* a_src2  = (float*)alloc((size_t)N_NODES * 4);
  float* a_dst2  = (float*)alloc((size_t)N_NODES * 4);
  int* counts    = (int*)alloc((size_t)N_NODES * 4);
  int* cursor    = (int*)alloc((size_t)N_NODES * 4);
  int* indptr    = (int*)alloc((size_t)(N_NODES + 1) * 4);
  int* blocksums = (int*)alloc(256 * 4);
  int* csr_src   = (int*)alloc((size_t)N_ETOT * 4);

  hipMemsetAsync(counts, 0, (size_t)N_NODES * 4, stream);
  hipMemsetAsync(cursor, 0, (size_t)N_NODES * 4, stream);

  gemm1_kernel<<<(N_NODES + 63) / 64, 256, 0, stream>>>(
      x, W1, att_src1, att_dst1, h1b, a_src1, a_dst1, N_NODES);

  hist_kernel<<<(N_ETOT + 255) / 256, 256, 0, stream>>>(dst_idx, counts);
  int nb = (N_NODES + 255) / 256;
  scan_block_kernel<<<nb, 256, 0, stream>>>(counts, indptr, blocksums, N_NODES);
  scan_top_kernel<<<1, 256, 0, stream>>>(blocksums, nb);
  scan_add_kernel<<<nb, 256, 0, stream>>>(indptr, blocksums, N_NODES, N_ETOT);
  scatter_kernel<<<(N_ETOT + 255) / 256, 256, 0, stream>>>(
      src_idx, dst_idx, indptr, cursor, csr_src);

  agg1_kernel<<<N_NODES / 4, 256, 0, stream>>>(
      indptr, csr_src, h1b, a_src1, a_dst1, bias1, h_elu, N_NODES);

  gemm2_kernel<<<(N_NODES + 63) / 64, 256, 0, stream>>>(
      h_elu, W2, att_src2, att_dst2, h2b, a_src2, a_dst2, N_NODES);

  agg2_kernel<<<N_NODES / 4, 256, 0, stream>>>(
      indptr, csr_src, h2b, a_src2, a_dst2, bias2, (float*)d_out, N_NODES);
}

// Round 3
// 487.461 us; speedup vs baseline: 1.1743x; 1.0241x over previous
//
#include <hip/hip_runtime.h>
#include <cstddef>

#define N_NODES 50000
#define N_EDGES 1600000
#define N_ETOT  (N_EDGES + N_NODES)
#define F_IN    512
#define HEADS   8
#define HID     8
#define CLS     16

typedef float v4 __attribute__((ext_vector_type(4)));
typedef float v2 __attribute__((ext_vector_type(2)));
typedef unsigned short us4 __attribute__((ext_vector_type(4)));
typedef unsigned int u4 __attribute__((ext_vector_type(4)));

__device__ inline float b2f_lo(unsigned int u) { return __uint_as_float(u << 16); }
__device__ inline float b2f_hi(unsigned int u) { return __uint_as_float(u & 0xffff0000u); }
__device__ inline unsigned short f2b(float f) {
  unsigned int x = __float_as_uint(f);
  unsigned int r = (x + 0x7fffu + ((x >> 16) & 1u)) >> 16;   // RNE
  return (unsigned short)r;
}

// ---- GEMM1: x(50000x512) @ W1(512x64) -> h1b(bf16) + attn logits epilogue ----
__global__ __launch_bounds__(256) void gemm1_kernel(
    const float* __restrict__ x, const float* __restrict__ W,
    const float* __restrict__ att_src, const float* __restrict__ att_dst,
    unsigned short* __restrict__ h1b, float* __restrict__ a_src,
    float* __restrict__ a_dst, int nrows) {
  __shared__ float xs[64][36];
  __shared__ float ws[32][68];
  int t  = threadIdx.x;
  int tx = t & 15, ty = t >> 4;
  int row0 = blockIdx.x * 64;
  v4 acc[4];
  acc[0] = 0.f; acc[1] = 0.f; acc[2] = 0.f; acc[3] = 0.f;

  for (int k0 = 0; k0 < F_IN; k0 += 32) {
#pragma unroll
    for (int r = 0; r < 2; ++r) {
      int idx = t + r * 256;
      int m = idx >> 3;
      int kk = (idx & 7) * 4;
      v4 v = 0.f;
      int grow = row0 + m;
      if (grow < nrows) v = *(const v4*)(x + (size_t)grow * F_IN + k0 + kk);
      *(v4*)&xs[m][kk] = v;
    }
#pragma unroll
    for (int r = 0; r < 2; ++r) {
      int idx = t + r * 256;
      int kk = idx >> 4;
      int nn = (idx & 15) * 4;
      *(v4*)&ws[kk][nn] = *(const v4*)(W + (size_t)(k0 + kk) * 64 + nn);
    }
    __syncthreads();
#pragma unroll
    for (int kk = 0; kk < 32; kk += 4) {
      v4 a[4], b[4];
#pragma unroll
      for (int i = 0; i < 4; ++i) a[i] = *(const v4*)&xs[ty * 4 + i][kk];
#pragma unroll
      for (int tt = 0; tt < 4; ++tt) b[tt] = *(const v4*)&ws[kk + tt][tx * 4];
#pragma unroll
      for (int i = 0; i < 4; ++i) {
        acc[i] += a[i][0] * b[0];
        acc[i] += a[i][1] * b[1];
        acc[i] += a[i][2] * b[2];
        acc[i] += a[i][3] * b[3];
      }
    }
    __syncthreads();
  }
  v4 avs = *(const v4*)(att_src + tx * 4);
  v4 avd = *(const v4*)(att_dst + tx * 4);
#pragma unroll
  for (int i = 0; i < 4; ++i) {
    int grow = row0 + ty * 4 + i;
    float ps = acc[i][0]*avs[0] + acc[i][1]*avs[1] + acc[i][2]*avs[2] + acc[i][3]*avs[3];
    float pd = acc[i][0]*avd[0] + acc[i][1]*avd[1] + acc[i][2]*avd[2] + acc[i][3]*avd[3];
    ps += __shfl_xor(ps, 1);
    pd += __shfl_xor(pd, 1);
    if (grow < nrows) {
      us4 o;
      o.x = f2b(acc[i][0]); o.y = f2b(acc[i][1]);
      o.z = f2b(acc[i][2]); o.w = f2b(acc[i][3]);
      *(us4*)(h1b + (size_t)grow * 64 + tx * 4) = o;
      if (!(tx & 1)) {
        int head = tx >> 1;
        a_src[grow * 8 + head] = ps;
        a_dst[grow * 8 + head] = pd;
      }
    }
  }
}

// --------------------------- CSR build ----------------------------------------
__global__ __launch_bounds__(256) void hist_kernel(
    const int* __restrict__ dst_idx, int* __restrict__ counts) {
  int e = blockIdx.x * 256 + threadIdx.x;
  if (e >= N_ETOT) return;
  int d = (e < N_EDGES) ? dst_idx[e] : (e - N_EDGES);
  atomicAdd(&counts[d], 1);
}

__global__ __launch_bounds__(256) void scan_block_kernel(
    const int* __restrict__ counts, int* __restrict__ indptr,
    int* __restrict__ blocksums, int n) {
  __shared__ int sm[256];
  int t = threadIdx.x;
  int i = blockIdx.x * 256 + t;
  int v = (i < n) ? counts[i] : 0;
  sm[t] = v;
  __syncthreads();
  for (int o = 1; o < 256; o <<= 1) {
    int u = (t >= o) ? sm[t - o] : 0;
    __syncthreads();
    sm[t] += u;
    __syncthreads();
  }
  if (i < n) indptr[i] = sm[t] - v;
  if (t == 255) blocksums[blockIdx.x] = sm[255];
}

__global__ __launch_bounds__(256) void scan_top_kernel(int* __restrict__ bs, int nb) {
  __shared__ int sm[256];
  int t = threadIdx.x;
  int v = (t < nb) ? bs[t] : 0;
  sm[t] = v;
  __syncthreads();
  for (int o = 1; o < 256; o <<= 1) {
    int u = (t >= o) ? sm[t - o] : 0;
    __syncthreads();
    sm[t] += u;
    __syncthreads();
  }
  bs[t] = sm[t] - v;
}

// writes BOTH indptr and the scatter cursor copy
__global__ __launch_bounds__(256) void scan_add_kernel(
    int* __restrict__ indptr, int* __restrict__ cursor,
    const int* __restrict__ bs, int n, int total) {
  int i = blockIdx.x * 256 + threadIdx.x;
  if (i < n) {
    int v = indptr[i] + bs[blockIdx.x];
    indptr[i] = v;
    cursor[i] = v;
  }
  if (i == 0) indptr[n] = total;
}

__global__ __launch_bounds__(256) void scatter_kernel(
    const int* __restrict__ src_idx, const int* __restrict__ dst_idx,
    int* __restrict__ cursor, int* __restrict__ csr_src) {
  int e = blockIdx.x * 256 + threadIdx.x;
  if (e >= N_ETOT) return;
  int s, d;
  if (e < N_EDGES) { s = src_idx[e]; d = dst_idx[e]; }
  else             { s = d = e - N_EDGES; }
  int pos = atomicAdd(&cursor[d], 1);
  csr_src[pos] = s;
}

// ------------- layer-1 edge softmax + aggregate ---------------------------------
// wave = one node; lane = (edge-slot j = lane>>3, head h = lane&7)
// each lane: own w (no redundancy), 16B dwordx4 feature load (8 bf16 = head chunk)
__global__ __launch_bounds__(256) void agg1_kernel(
    const int* __restrict__ indptr, const int* __restrict__ csr_src,
    const unsigned short* __restrict__ h1b, const float* __restrict__ a_src1,
    const float* __restrict__ a_dst1, const float* __restrict__ bias1,
    float* __restrict__ h_elu, int n) {
  int wave = threadIdx.x >> 6;
  int lane = threadIdx.x & 63;
  int node = blockIdx.x * 4 + wave;
  if (node >= n) return;
  int j = lane >> 3;     // edge slot 0..7
  int h = lane & 7;      // head 0..7
  float adst = a_dst1[(unsigned)(node * 8 + h)];
  int beg = indptr[node], end = indptr[node + 1];
  float acc0=0.f, acc1=0.f, acc2=0.f, acc3=0.f, acc4=0.f, acc5=0.f, acc6=0.f, acc7=0.f;
  float den = 0.f;
  for (int base = beg; base < end; base += 64) {
    int m = end - base;
    if (m > 64) m = 64;
    int sv = (lane < m) ? csr_src[base + lane] : 0;
    for (int p = 0; p < m; p += 8) {
      int s = __shfl(sv, p + j);
      bool act = (p + j) < m;
      float e = a_src1[(unsigned)(s * 8 + h)] + adst;
      e = (e > 0.f) ? e : 0.2f * e;
      float w = act ? __expf(e) : 0.f;
      den += w;
      u4 f = *(const u4*)(h1b + (unsigned)(s * 64 + h * 8));
      acc0 += w * b2f_lo(f.x); acc1 += w * b2f_hi(f.x);
      acc2 += w * b2f_lo(f.y); acc3 += w * b2f_hi(f.y);
      acc4 += w * b2f_lo(f.z); acc5 += w * b2f_hi(f.z);
      acc6 += w * b2f_lo(f.w); acc7 += w * b2f_hi(f.w);
    }
  }
  // reduce over edge slots (lane bits 3..5)
#pragma unroll
  for (int o = 8; o < 64; o <<= 1) {
    den  += __shfl_xor(den, o);
    acc0 += __shfl_xor(acc0, o); acc1 += __shfl_xor(acc1, o);
    acc2 += __shfl_xor(acc2, o); acc3 += __shfl_xor(acc3, o);
    acc4 += __shfl_xor(acc4, o); acc5 += __shfl_xor(acc5, o);
    acc6 += __shfl_xor(acc6, o); acc7 += __shfl_xor(acc7, o);
  }
  if (j == 0) {
    float inv = 1.f / den;
    v4 b0 = *(const v4*)(bias1 + h * 8);
    v4 b1 = *(const v4*)(bias1 + h * 8 + 4);
    v4 o0, o1;
    o0[0] = acc0 * inv + b0[0]; o0[1] = acc1 * inv + b0[1];
    o0[2] = acc2 * inv + b0[2]; o0[3] = acc3 * inv + b0[3];
    o1[0] = acc4 * inv + b1[0]; o1[1] = acc5 * inv + b1[1];
    o1[2] = acc6 * inv + b1[2]; o1[3] = acc7 * inv + b1[3];
#pragma unroll
    for (int k = 0; k < 4; ++k) {
      o0[k] = (o0[k] > 0.f) ? o0[k] : expm1f(o0[k]);
      o1[k] = (o1[k] > 0.f) ? o1[k] : expm1f(o1[k]);
    }
    *(v4*)(h_elu + (size_t)node * 64 + h * 8)     = o0;
    *(v4*)(h_elu + (size_t)node * 64 + h * 8 + 4) = o1;
  }
}

// --------- GEMM2: h_elu(50000x64) @ W2(64x16) + attn2 logits epilogue ----------
__global__ __launch_bounds__(256) void gemm2_kernel(
    const float* __restrict__ h_elu, const float* __restrict__ W2,
    const float* __restrict__ att_src2, const float* __restrict__ att_dst2,
    unsigned short* __restrict__ h2b, float* __restrict__ a_src2,
    float* __restrict__ a_dst2, int n) {
  __shared__ float xs[64][68];
  __shared__ float ws[64][16];
  int t = threadIdx.x;
  int row0 = blockIdx.x * 64;
  {
    int k = t >> 2, c4 = (t & 3) * 4;
    *(v4*)&ws[k][c4] = *(const v4*)(W2 + (size_t)k * 16 + c4);
  }
#pragma unroll
  for (int r = 0; r < 4; ++r) {
    int idx = t + r * 256;
    int m = idx >> 4;
    int c4 = (idx & 15) * 4;
    v4 v = 0.f;
    int grow = row0 + m;
    if (grow < n) v = *(const v4*)(h_elu + (size_t)grow * 64 + c4);
    *(v4*)&xs[m][c4] = v;
  }
  __syncthreads();
  int r = t >> 2, q = t & 3;
  int grow = row0 + r;
  v4 acc = 0.f;
#pragma unroll
  for (int k = 0; k < 64; ++k) {
    acc += xs[r][k] * *(const v4*)&ws[k][q * 4];
  }
  v4 asv = *(const v4*)(att_src2 + q * 4);
  v4 adv = *(const v4*)(att_dst2 + q * 4);
  float ps = acc[0] * asv[0] + acc[1] * asv[1] + acc[2] * asv[2] + acc[3] * asv[3];
  float pd = acc[0] * adv[0] + acc[1] * adv[1] + acc[2] * adv[2] + acc[3] * adv[3];
  ps += __shfl_xor(ps, 1); ps += __shfl_xor(ps, 2);
  pd += __shfl_xor(pd, 1); pd += __shfl_xor(pd, 2);
  if (grow < n) {
    us4 o;
    o.x = f2b(acc[0]); o.y = f2b(acc[1]); o.z = f2b(acc[2]); o.w = f2b(acc[3]);
    *(us4*)(h2b + (size_t)grow * 16 + q * 4) = o;
    if (q == 0) { a_src2[grow] = ps; a_dst2[grow] = pd; }
  }
}

// ------- layer-2 aggregate + bias + log_softmax --------------------------------
// wave = one node; lane = (edge slot j = lane>>3, sub = lane&7 -> classes 2*sub,2*sub+1)
__global__ __launch_bounds__(256) void agg2_kernel(
    const int* __restrict__ indptr, const int* __restrict__ csr_src,
    const unsigned short* __restrict__ h2b, const float* __restrict__ a_src2,
    const float* __restrict__ a_dst2, const float* __restrict__ bias2,
    float* __restrict__ out, int n) {
  int wave = threadIdx.x >> 6;
  int lane = threadIdx.x & 63;
  int node = blockIdx.x * 4 + wave;
  if (node >= n) return;
  int j = lane >> 3;
  int sub = lane & 7;
  float adst = a_dst2[node];
  int beg = indptr[node], end = indptr[node + 1];
  float acc0 = 0.f, acc1 = 0.f, den = 0.f;
  for (int base = beg; base < end; base += 64) {
    int m = end - base;
    if (m > 64) m = 64;
    int sv = (lane < m) ? csr_src[base + lane] : 0;
    for (int p = 0; p < m; p += 8) {
      int s = __shfl(sv, p + j);
      bool act = (p + j) < m;
      float e = a_src2[(unsigned)s] + adst;
      e = (e > 0.f) ? e : 0.2f * e;
      float w = act ? __expf(e) : 0.f;
      den += w;
      unsigned int f = *(const unsigned int*)(h2b + (unsigned)(s * 16 + sub * 2));
      acc0 += w * b2f_lo(f);
      acc1 += w * b2f_hi(f);
    }
  }
#pragma unroll
  for (int o = 8; o < 64; o <<= 1) {
    den  += __shfl_xor(den, o);
    acc0 += __shfl_xor(acc0, o);
    acc1 += __shfl_xor(acc1, o);
  }
  float inv = 1.f / den;
  float v0 = acc0 * inv + bias2[sub * 2];
  float v1 = acc1 * inv + bias2[sub * 2 + 1];
  float mx = fmaxf(v0, v1);
#pragma unroll
  for (int o = 1; o < 8; o <<= 1) mx = fmaxf(mx, __shfl_xor(mx, o));
  float ss = __expf(v0 - mx) + __expf(v1 - mx);
#pragma unroll
  for (int o = 1; o < 8; o <<= 1) ss += __shfl_xor(ss, o);
  float lg = mx + __logf(ss);
  if (j == 0) {
    v2 r;
    r[0] = v0 - lg;
    r[1] = v1 - lg;
    *(v2*)(out + (size_t)node * 16 + sub * 2) = r;
  }
}

// ------------------------------------------------------------------------------
extern "C" void kernel_launch(void* const* d_in, const int* in_sizes, int n_in,
                              void* d_out, int out_size, void* d_ws, size_t ws_size,
                              hipStream_t stream) {
  const float* x        = (const float*)d_in[0];
  const int*   ei       = (const int*)d_in[1];
  const float* W1       = (const float*)d_in[2];
  const float* att_src1 = (const float*)d_in[3];
  const float* att_dst1 = (const float*)d_in[4];
  const float* bias1    = (const float*)d_in[5];
  const float* W2       = (const float*)d_in[6];
  const float* att_src2 = (const float*)d_in[7];
  const float* att_dst2 = (const float*)d_in[8];
  const float* bias2    = (const float*)d_in[9];
  const int* src_idx = ei;
  const int* dst_idx = ei + N_EDGES;

  char* p = (char*)d_ws;
  auto alloc = [&](size_t bytes) {
    void* r = (void*)p;
    p += (bytes + 255) & ~(size_t)255;
    return r;
  };
  unsigned short* h1b = (unsigned short*)alloc((size_t)N_NODES * 64 * 2);
  float* h_elu   = (float*)alloc((size_t)N_NODES * 64 * 4);
  float* a_src1  = (float*)alloc((size_t)N_NODES * 8 * 4);
  float* a_dst1  = (float*)alloc((size_t)N_NODES * 8 * 4);
  unsigned short* h2b = (unsigned short*)alloc((size_t)N_NODES * 16 * 2);
  float* a_src2  = (float*)alloc((size_t)N_NODES * 4);
  float* a_dst2  = (float*)alloc((size_t)N_NODES * 4);
  int* counts    = (int*)alloc((size_t)N_NODES * 4);
  int* cursor    = (int*)alloc((size_t)N_NODES * 4);
  int* indptr    = (int*)alloc((size_t)(N_NODES + 1) * 4);
  int* blocksums = (int*)alloc(256 * 4);
  int* csr_src   = (int*)alloc((size_t)N_ETOT * 4);

  hipMemsetAsync(counts, 0, (size_t)N_NODES * 4, stream);

  gemm1_kernel<<<(N_NODES + 63) / 64, 256, 0, stream>>>(
      x, W1, att_src1, att_dst1, h1b, a_src1, a_dst1, N_NODES);

  hist_kernel<<<(N_ETOT + 255) / 256, 256, 0, stream>>>(dst_idx, counts);
  int nb = (N_NODES + 255) / 256;
  scan_block_kernel<<<nb, 256, 0, stream>>>(counts, indptr, blocksums, N_NODES);
  scan_top_kernel<<<1, 256, 0, stream>>>(blocksums, nb);
  scan_add_kernel<<<nb, 256, 0, stream>>>(indptr, cursor, blocksums, N_NODES, N_ETOT);
  scatter_kernel<<<(N_ETOT + 255) / 256, 256, 0, stream>>>(
      src_idx, dst_idx, cursor, csr_src);

  agg1_kernel<<<N_NODES / 4, 256, 0, stream>>>(
      indptr, csr_src, h1b, a_src1, a_dst1, bias1, h_elu, N_NODES);

  gemm2_kernel<<<(N_NODES + 63) / 64, 256, 0, stream>>>(
      h_elu, W2, att_src2, att_dst2, h2b, a_src2, a_dst2, N_NODES);

  agg2_kernel<<<N_NODES / 4, 256, 0, stream>>>(
      indptr, csr_src, h2b, a_src2, a_dst2, bias2, (float*)d_out, N_NODES);
}

// Round 4
// 342.301 us; speedup vs baseline: 1.6722x; 1.4241x over previous
//
#include <hip/hip_runtime.h>
#include <cstddef>

#define N_NODES 50000
#define N_EDGES 1600000
#define N_ETOT  (N_EDGES + N_NODES)
#define F_IN    512
#define HEADS   8
#define HID     8
#define CLS     16

#define NBUCK   196      // ceil(50000/256) dst buckets
#define BCAP    12288    // per-bucket capacity (mean load 8163, +45 sigma)
#define CHUNKA  4096     // edges per block in phase A

typedef float v4 __attribute__((ext_vector_type(4)));
typedef float v2 __attribute__((ext_vector_type(2)));
typedef unsigned short us4 __attribute__((ext_vector_type(4)));
typedef unsigned int u4 __attribute__((ext_vector_type(4)));

__device__ inline float b2f_lo(unsigned int u) { return __uint_as_float(u << 16); }
__device__ inline float b2f_hi(unsigned int u) { return __uint_as_float(u & 0xffff0000u); }
__device__ inline unsigned short f2b(float f) {
  unsigned int x = __float_as_uint(f);
  unsigned int r = (x + 0x7fffu + ((x >> 16) & 1u)) >> 16;   // RNE
  return (unsigned short)r;
}

// ---- GEMM1: x(50000x512) @ W1(512x64) -> h1b(bf16) + attn logits epilogue ----
__global__ __launch_bounds__(256) void gemm1_kernel(
    const float* __restrict__ x, const float* __restrict__ W,
    const float* __restrict__ att_src, const float* __restrict__ att_dst,
    unsigned short* __restrict__ h1b, float* __restrict__ a_src,
    float* __restrict__ a_dst, int nrows) {
  __shared__ float xs[64][36];
  __shared__ float ws[32][68];
  int t  = threadIdx.x;
  int tx = t & 15, ty = t >> 4;
  int row0 = blockIdx.x * 64;
  v4 acc[4];
  acc[0] = 0.f; acc[1] = 0.f; acc[2] = 0.f; acc[3] = 0.f;

  for (int k0 = 0; k0 < F_IN; k0 += 32) {
#pragma unroll
    for (int r = 0; r < 2; ++r) {
      int idx = t + r * 256;
      int m = idx >> 3;
      int kk = (idx & 7) * 4;
      v4 v = 0.f;
      int grow = row0 + m;
      if (grow < nrows) v = *(const v4*)(x + (size_t)grow * F_IN + k0 + kk);
      *(v4*)&xs[m][kk] = v;
    }
#pragma unroll
    for (int r = 0; r < 2; ++r) {
      int idx = t + r * 256;
      int kk = idx >> 4;
      int nn = (idx & 15) * 4;
      *(v4*)&ws[kk][nn] = *(const v4*)(W + (size_t)(k0 + kk) * 64 + nn);
    }
    __syncthreads();
#pragma unroll
    for (int kk = 0; kk < 32; kk += 4) {
      v4 a[4], b[4];
#pragma unroll
      for (int i = 0; i < 4; ++i) a[i] = *(const v4*)&xs[ty * 4 + i][kk];
#pragma unroll
      for (int tt = 0; tt < 4; ++tt) b[tt] = *(const v4*)&ws[kk + tt][tx * 4];
#pragma unroll
      for (int i = 0; i < 4; ++i) {
        acc[i] += a[i][0] * b[0];
        acc[i] += a[i][1] * b[1];
        acc[i] += a[i][2] * b[2];
        acc[i] += a[i][3] * b[3];
      }
    }
    __syncthreads();
  }
  v4 avs = *(const v4*)(att_src + tx * 4);
  v4 avd = *(const v4*)(att_dst + tx * 4);
#pragma unroll
  for (int i = 0; i < 4; ++i) {
    int grow = row0 + ty * 4 + i;
    float ps = acc[i][0]*avs[0] + acc[i][1]*avs[1] + acc[i][2]*avs[2] + acc[i][3]*avs[3];
    float pd = acc[i][0]*avd[0] + acc[i][1]*avd[1] + acc[i][2]*avd[2] + acc[i][3]*avd[3];
    ps += __shfl_xor(ps, 1);
    pd += __shfl_xor(pd, 1);
    if (grow < nrows) {
      us4 o;
      o.x = f2b(acc[i][0]); o.y = f2b(acc[i][1]);
      o.z = f2b(acc[i][2]); o.w = f2b(acc[i][3]);
      *(us4*)(h1b + (size_t)grow * 64 + tx * 4) = o;
      if (!(tx & 1)) {
        int head = tx >> 1;
        a_src[grow * 8 + head] = ps;
        a_dst[grow * 8 + head] = pd;
      }
    }
  }
}

// --------------------------- CSR build (bucketed, 3 kernels) -------------------
// Phase A: bucket edges by dst>>8; packed entry = (src<<8)|(dst&255)
__global__ __launch_bounds__(256) void bucketA_kernel(
    const int* __restrict__ src_idx, const int* __restrict__ dst_idx,
    int* __restrict__ gcur, int* __restrict__ abuck) {
  __shared__ int hist[NBUCK];
  __shared__ int base[NBUCK];
  __shared__ int cur[NBUCK];
  int t = threadIdx.x;
  if (t < NBUCK) hist[t] = 0;
  __syncthreads();
  int e0 = blockIdx.x * CHUNKA;
  int eend = e0 + CHUNKA;
  if (eend > N_EDGES) eend = N_EDGES;
  for (int e = e0 + t; e < eend; e += 256)
    atomicAdd(&hist[(unsigned)dst_idx[e] >> 8], 1);
  __syncthreads();
  if (t < NBUCK) {
    int c = hist[t];
    base[t] = c ? atomicAdd(&gcur[t], c) : 0;
    cur[t] = 0;
  }
  __syncthreads();
  for (int e = e0 + t; e < eend; e += 256) {
    int s = src_idx[e];
    int d = dst_idx[e];
    int b = (unsigned)d >> 8;
    int r = atomicAdd(&cur[b], 1);
    abuck[b * BCAP + base[b] + r] = (s << 8) | (d & 255);
  }
}

// scan bucket totals (edges + self-loops) -> bucket_base; also indptr[N]
__global__ __launch_bounds__(256) void bucket_scan_kernel(
    const int* __restrict__ gcur, int* __restrict__ bucket_base,
    int* __restrict__ indptr) {
  __shared__ int sm[256];
  int t = threadIdx.x;
  int nnodes = N_NODES - t * 256;
  if (nnodes > 256) nnodes = 256;
  if (nnodes < 0) nnodes = 0;
  int v = (t < NBUCK) ? gcur[t] + nnodes : 0;
  sm[t] = v;
  __syncthreads();
  for (int o = 1; o < 256; o <<= 1) {
    int u = (t >= o) ? sm[t - o] : 0;
    __syncthreads();
    sm[t] += u;
    __syncthreads();
  }
  if (t < NBUCK) bucket_base[t] = sm[t] - v;   // exclusive
  if (t == 0) indptr[N_NODES] = N_ETOT;
}

// Phase B: one block per bucket -> per-node indptr + dense csr_src scatter
__global__ __launch_bounds__(256) void bucketB_kernel(
    const int* __restrict__ gcur, const int* __restrict__ bucket_base,
    const int* __restrict__ abuck, int* __restrict__ indptr,
    int* __restrict__ csr_src) {
  __shared__ int hist[256];
  __shared__ int sm[256];
  __shared__ int cur[256];
  int b = blockIdx.x;
  int t = threadIdx.x;
  int M = gcur[b];
  int node0 = b * 256;
  int nnodes = N_NODES - node0;
  if (nnodes > 256) nnodes = 256;
  hist[t] = (t < nnodes) ? 1 : 0;   // self-loop
  __syncthreads();
  const int* ab = abuck + b * BCAP;
  for (int i = t; i < M; i += 256)
    atomicAdd(&hist[ab[i] & 255], 1);
  __syncthreads();
  int v = hist[t];
  sm[t] = v;
  __syncthreads();
  for (int o = 1; o < 256; o <<= 1) {
    int u = (t >= o) ? sm[t - o] : 0;
    __syncthreads();
    sm[t] += u;
    __syncthreads();
  }
  int bbase = bucket_base[b];
  int excl = sm[t] - v;
  cur[t] = excl;
  if (t < nnodes) indptr[node0 + t] = bbase + excl;
  __syncthreads();
  for (int i = t; i < M; i += 256) {
    int entry = ab[i];
    int r = atomicAdd(&cur[entry & 255], 1);
    csr_src[bbase + r] = entry >> 8;
  }
  if (t < nnodes) {
    int r = atomicAdd(&cur[t], 1);
    csr_src[bbase + r] = node0 + t;
  }
}

// ------------- layer-1 edge softmax + aggregate ---------------------------------
__global__ __launch_bounds__(256) void agg1_kernel(
    const int* __restrict__ indptr, const int* __restrict__ csr_src,
    const unsigned short* __restrict__ h1b, const float* __restrict__ a_src1,
    const float* __restrict__ a_dst1, const float* __restrict__ bias1,
    float* __restrict__ h_elu, int n) {
  int wave = threadIdx.x >> 6;
  int lane = threadIdx.x & 63;
  int node = blockIdx.x * 4 + wave;
  if (node >= n) return;
  int j = lane >> 3;     // edge slot 0..7
  int h = lane & 7;      // head 0..7
  float adst = a_dst1[(unsigned)(node * 8 + h)];
  int beg = indptr[node], end = indptr[node + 1];
  float acc0=0.f, acc1=0.f, acc2=0.f, acc3=0.f, acc4=0.f, acc5=0.f, acc6=0.f, acc7=0.f;
  float den = 0.f;
  for (int base = beg; base < end; base += 64) {
    int m = end - base;
    if (m > 64) m = 64;
    int sv = (lane < m) ? csr_src[base + lane] : 0;
    for (int p = 0; p < m; p += 8) {
      int s = __shfl(sv, p + j);
      bool act = (p + j) < m;
      float e = a_src1[(unsigned)(s * 8 + h)] + adst;
      e = (e > 0.f) ? e : 0.2f * e;
      float w = act ? __expf(e) : 0.f;
      den += w;
      u4 f = *(const u4*)(h1b + (unsigned)(s * 64 + h * 8));
      acc0 += w * b2f_lo(f.x); acc1 += w * b2f_hi(f.x);
      acc2 += w * b2f_lo(f.y); acc3 += w * b2f_hi(f.y);
      acc4 += w * b2f_lo(f.z); acc5 += w * b2f_hi(f.z);
      acc6 += w * b2f_lo(f.w); acc7 += w * b2f_hi(f.w);
    }
  }
#pragma unroll
  for (int o = 8; o < 64; o <<= 1) {
    den  += __shfl_xor(den, o);
    acc0 += __shfl_xor(acc0, o); acc1 += __shfl_xor(acc1, o);
    acc2 += __shfl_xor(acc2, o); acc3 += __shfl_xor(acc3, o);
    acc4 += __shfl_xor(acc4, o); acc5 += __shfl_xor(acc5, o);
    acc6 += __shfl_xor(acc6, o); acc7 += __shfl_xor(acc7, o);
  }
  if (j == 0) {
    float inv = 1.f / den;
    v4 b0 = *(const v4*)(bias1 + h * 8);
    v4 b1 = *(const v4*)(bias1 + h * 8 + 4);
    v4 o0, o1;
    o0[0] = acc0 * inv + b0[0]; o0[1] = acc1 * inv + b0[1];
    o0[2] = acc2 * inv + b0[2]; o0[3] = acc3 * inv + b0[3];
    o1[0] = acc4 * inv + b1[0]; o1[1] = acc5 * inv + b1[1];
    o1[2] = acc6 * inv + b1[2]; o1[3] = acc7 * inv + b1[3];
#pragma unroll
    for (int k = 0; k < 4; ++k) {
      o0[k] = (o0[k] > 0.f) ? o0[k] : expm1f(o0[k]);
      o1[k] = (o1[k] > 0.f) ? o1[k] : expm1f(o1[k]);
    }
    *(v4*)(h_elu + (size_t)node * 64 + h * 8)     = o0;
    *(v4*)(h_elu + (size_t)node * 64 + h * 8 + 4) = o1;
  }
}

// --------- GEMM2: h_elu(50000x64) @ W2(64x16) + attn2 logits epilogue ----------
__global__ __launch_bounds__(256) void gemm2_kernel(
    const float* __restrict__ h_elu, const float* __restrict__ W2,
    const float* __restrict__ att_src2, const float* __restrict__ att_dst2,
    unsigned short* __restrict__ h2b, float* __restrict__ a_src2,
    float* __restrict__ a_dst2, int n) {
  __shared__ float xs[64][68];
  __shared__ float ws[64][16];
  int t = threadIdx.x;
  int row0 = blockIdx.x * 64;
  {
    int k = t >> 2, c4 = (t & 3) * 4;
    *(v4*)&ws[k][c4] = *(const v4*)(W2 + (size_t)k * 16 + c4);
  }
#pragma unroll
  for (int r = 0; r < 4; ++r) {
    int idx = t + r * 256;
    int m = idx >> 4;
    int c4 = (idx & 15) * 4;
    v4 v = 0.f;
    int grow = row0 + m;
    if (grow < n) v = *(const v4*)(h_elu + (size_t)grow * 64 + c4);
    *(v4*)&xs[m][c4] = v;
  }
  __syncthreads();
  int r = t >> 2, q = t & 3;
  int grow = row0 + r;
  v4 acc = 0.f;
#pragma unroll
  for (int k = 0; k < 64; ++k) {
    acc += xs[r][k] * *(const v4*)&ws[k][q * 4];
  }
  v4 asv = *(const v4*)(att_src2 + q * 4);
  v4 adv = *(const v4*)(att_dst2 + q * 4);
  float ps = acc[0] * asv[0] + acc[1] * asv[1] + acc[2] * asv[2] + acc[3] * asv[3];
  float pd = acc[0] * adv[0] + acc[1] * adv[1] + acc[2] * adv[2] + acc[3] * adv[3];
  ps += __shfl_xor(ps, 1); ps += __shfl_xor(ps, 2);
  pd += __shfl_xor(pd, 1); pd += __shfl_xor(pd, 2);
  if (grow < n) {
    us4 o;
    o.x = f2b(acc[0]); o.y = f2b(acc[1]); o.z = f2b(acc[2]); o.w = f2b(acc[3]);
    *(us4*)(h2b + (size_t)grow * 16 + q * 4) = o;
    if (q == 0) { a_src2[grow] = ps; a_dst2[grow] = pd; }
  }
}

// ------- layer-2 aggregate + bias + log_softmax --------------------------------
__global__ __launch_bounds__(256) void agg2_kernel(
    const int* __restrict__ indptr, const int* __restrict__ csr_src,
    const unsigned short* __restrict__ h2b, const float* __restrict__ a_src2,
    const float* __restrict__ a_dst2, const float* __restrict__ bias2,
    float* __restrict__ out, int n) {
  int wave = threadIdx.x >> 6;
  int lane = threadIdx.x & 63;
  int node = blockIdx.x * 4 + wave;
  if (node >= n) return;
  int j = lane >> 3;
  int sub = lane & 7;
  float adst = a_dst2[node];
  int beg = indptr[node], end = indptr[node + 1];
  float acc0 = 0.f, acc1 = 0.f, den = 0.f;
  for (int base = beg; base < end; base += 64) {
    int m = end - base;
    if (m > 64) m = 64;
    int sv = (lane < m) ? csr_src[base + lane] : 0;
    for (int p = 0; p < m; p += 8) {
      int s = __shfl(sv, p + j);
      bool act = (p + j) < m;
      float e = a_src2[(unsigned)s] + adst;
      e = (e > 0.f) ? e : 0.2f * e;
      float w = act ? __expf(e) : 0.f;
      den += w;
      unsigned int f = *(const unsigned int*)(h2b + (unsigned)(s * 16 + sub * 2));
      acc0 += w * b2f_lo(f);
      acc1 += w * b2f_hi(f);
    }
  }
#pragma unroll
  for (int o = 8; o < 64; o <<= 1) {
    den  += __shfl_xor(den, o);
    acc0 += __shfl_xor(acc0, o);
    acc1 += __shfl_xor(acc1, o);
  }
  float inv = 1.f / den;
  float v0 = acc0 * inv + bias2[sub * 2];
  float v1 = acc1 * inv + bias2[sub * 2 + 1];
  float mx = fmaxf(v0, v1);
#pragma unroll
  for (int o = 1; o < 8; o <<= 1) mx = fmaxf(mx, __shfl_xor(mx, o));
  float ss = __expf(v0 - mx) + __expf(v1 - mx);
#pragma unroll
  for (int o = 1; o < 8; o <<= 1) ss += __shfl_xor(ss, o);
  float lg = mx + __logf(ss);
  if (j == 0) {
    v2 r;
    r[0] = v0 - lg;
    r[1] = v1 - lg;
    *(v2*)(out + (size_t)node * 16 + sub * 2) = r;
  }
}

// ------------------------------------------------------------------------------
extern "C" void kernel_launch(void* const* d_in, const int* in_sizes, int n_in,
                              void* d_out, int out_size, void* d_ws, size_t ws_size,
                              hipStream_t stream) {
  const float* x        = (const float*)d_in[0];
  const int*   ei       = (const int*)d_in[1];
  const float* W1       = (const float*)d_in[2];
  const float* att_src1 = (const float*)d_in[3];
  const float* att_dst1 = (const float*)d_in[4];
  const float* bias1    = (const float*)d_in[5];
  const float* W2       = (const float*)d_in[6];
  const float* att_src2 = (const float*)d_in[7];
  const float* att_dst2 = (const float*)d_in[8];
  const float* bias2    = (const float*)d_in[9];
  const int* src_idx = ei;
  const int* dst_idx = ei + N_EDGES;

  char* p = (char*)d_ws;
  auto alloc = [&](size_t bytes) {
    void* r = (void*)p;
    p += (bytes + 255) & ~(size_t)255;
    return r;
  };
  unsigned short* h1b = (unsigned short*)alloc((size_t)N_NODES * 64 * 2);
  float* h_elu   = (float*)alloc((size_t)N_NODES * 64 * 4);
  float* a_src1  = (float*)alloc((size_t)N_NODES * 8 * 4);
  float* a_dst1  = (float*)alloc((size_t)N_NODES * 8 * 4);
  unsigned short* h2b = (unsigned short*)alloc((size_t)N_NODES * 16 * 2);
  float* a_src2  = (float*)alloc((size_t)N_NODES * 4);
  float* a_dst2  = (float*)alloc((size_t)N_NODES * 4);
  int* indptr    = (int*)alloc((size_t)(N_NODES + 1) * 4);
  int* gcur      = (int*)alloc((size_t)NBUCK * 4);
  int* bucket_base = (int*)alloc((size_t)(NBUCK + 1) * 4);
  int* csr_src   = (int*)alloc((size_t)N_ETOT * 4);
  // abuck (9.6 MB) aliases h_elu (12.8 MB): build finishes before agg1 writes h_elu
  int* abuck     = (int*)h_elu;

  hipMemsetAsync(gcur, 0, (size_t)NBUCK * 4, stream);

  gemm1_kernel<<<(N_NODES + 63) / 64, 256, 0, stream>>>(
      x, W1, att_src1, att_dst1, h1b, a_src1, a_dst1, N_NODES);

  bucketA_kernel<<<(N_EDGES + CHUNKA - 1) / CHUNKA, 256, 0, stream>>>(
      src_idx, dst_idx, gcur, abuck);
  bucket_scan_kernel<<<1, 256, 0, stream>>>(gcur, bucket_base, indptr);
  bucketB_kernel<<<NBUCK, 256, 0, stream>>>(
      gcur, bucket_base, abuck, indptr, csr_src);

  agg1_kernel<<<N_NODES / 4, 256, 0, stream>>>(
      indptr, csr_src, h1b, a_src1, a_dst1, bias1, h_elu, N_NODES);

  gemm2_kernel<<<(N_NODES + 63) / 64, 256, 0, stream>>>(
      h_elu, W2, att_src2, att_dst2, h2b, a_src2, a_dst2, N_NODES);

  agg2_kernel<<<N_NODES / 4, 256, 0, stream>>>(
      indptr, csr_src, h2b, a_src2, a_dst2, bias2, (float*)d_out, N_NODES);
}

// Round 5
// 323.758 us; speedup vs baseline: 1.7680x; 1.0573x over previous
//
#include <hip/hip_runtime.h>
#include <cstddef>

#define N_NODES 50000
#define N_EDGES 1600000
#define N_ETOT  (N_EDGES + N_NODES)
#define F_IN    512
#define HEADS   8
#define HID     8
#define CLS     16

#define NBUCK   196      // ceil(50000/256) dst buckets
#define BCAP    12288    // per-bucket capacity
#define CHUNKA  4096     // edges per block in phase A

typedef float v4 __attribute__((ext_vector_type(4)));
typedef float v2 __attribute__((ext_vector_type(2)));
typedef unsigned short us4 __attribute__((ext_vector_type(4)));
typedef unsigned int u4 __attribute__((ext_vector_type(4)));
typedef short bfrag __attribute__((ext_vector_type(8)));   // 8 bf16 = 4 VGPRs
typedef float ffrag __attribute__((ext_vector_type(4)));   // MFMA acc

__device__ inline float b2f_lo(unsigned int u) { return __uint_as_float(u << 16); }
__device__ inline float b2f_hi(unsigned int u) { return __uint_as_float(u & 0xffff0000u); }
__device__ inline unsigned short f2b(float f) {
  unsigned int x = __float_as_uint(f);
  unsigned int r = (x + 0x7fffu + ((x >> 16) & 1u)) >> 16;   // RNE
  return (unsigned short)r;
}

// ---- W1 (512x64 fp32) -> W1bT (64x512 bf16) ----------------------------------
__global__ __launch_bounds__(256) void w1t_kernel(
    const float* __restrict__ W, unsigned short* __restrict__ WT) {
  int t = blockIdx.x * 256 + threadIdx.x;
  if (t >= F_IN * 64) return;
  int k = t >> 6, n = t & 63;
  WT[n * F_IN + k] = f2b(W[t]);
}

// ---- GEMM1 (MFMA): x(50000x512 fp32) @ W1 -> h1b(bf16) + attn logits ---------
__global__ __launch_bounds__(256) void gemm1_kernel(
    const float* __restrict__ x, const unsigned short* __restrict__ W1bT,
    const float* __restrict__ att_src, const float* __restrict__ att_dst,
    unsigned short* __restrict__ h1b, float* __restrict__ a_src,
    float* __restrict__ a_dst, int nrows) {
  __shared__ unsigned short xsb[64][72];   // pad 64->72 (2-way bank alias: free)
  __shared__ unsigned short wsb[64][72];
  int t = threadIdx.x;
  int lane = t & 63;
  int w = t >> 6;                          // wave id -> m-strip
  int row0 = blockIdx.x * 64;
  ffrag acc[4];
  acc[0] = 0.f; acc[1] = 0.f; acc[2] = 0.f; acc[3] = 0.f;

  int mrow = lane & 15;
  int koff = (lane >> 4) * 8;

  for (int kt = 0; kt < 8; ++kt) {
    int k0 = kt * 64;
    // stage x tile 64m x 64k: fp32 -> bf16
#pragma unroll
    for (int r = 0; r < 4; ++r) {
      int slot = t + r * 256;
      int m = slot >> 4;
      int k4 = (slot & 15) * 4;
      v4 v = 0.f;
      int grow = row0 + m;
      if (grow < nrows) v = *(const v4*)(x + (size_t)grow * F_IN + k0 + k4);
      us4 o;
      o.x = f2b(v[0]); o.y = f2b(v[1]); o.z = f2b(v[2]); o.w = f2b(v[3]);
      *(us4*)&xsb[m][k4] = o;
    }
    // stage W tile 64n x 64k (already bf16, [n][k] layout)
#pragma unroll
    for (int r = 0; r < 2; ++r) {
      int slot = t + r * 256;
      int nn = slot >> 3;
      int k8 = (slot & 7) * 8;
      *(bfrag*)&wsb[nn][k8] = *(const bfrag*)(W1bT + nn * F_IN + k0 + k8);
    }
    __syncthreads();
#pragma unroll
    for (int kk = 0; kk < 64; kk += 32) {
      bfrag a = *(const bfrag*)&xsb[w * 16 + mrow][kk + koff];
#pragma unroll
      for (int tt = 0; tt < 4; ++tt) {
        bfrag b = *(const bfrag*)&wsb[tt * 16 + mrow][kk + koff];
        acc[tt] = __builtin_amdgcn_mfma_f32_16x16x32_bf16(a, b, acc[tt], 0, 0, 0);
      }
    }
    __syncthreads();
  }
  // epilogue: C/D layout col=lane&15, row=quad*4+reg
  int c = lane & 15, q = lane >> 4;
  float as_[4], ad_[4];
#pragma unroll
  for (int tt = 0; tt < 4; ++tt) {
    as_[tt] = att_src[tt * 16 + c];
    ad_[tt] = att_dst[tt * 16 + c];
  }
#pragma unroll
  for (int r = 0; r < 4; ++r) {
    int grow = row0 + w * 16 + q * 4 + r;
    float ps[4], pd[4];
#pragma unroll
    for (int tt = 0; tt < 4; ++tt) {
      ps[tt] = acc[tt][r] * as_[tt];
      pd[tt] = acc[tt][r] * ad_[tt];
    }
    // per-head sums: head of col n = n>>3; reduce over c bits 0..2
#pragma unroll
    for (int o = 1; o < 8; o <<= 1) {
#pragma unroll
      for (int tt = 0; tt < 4; ++tt) {
        ps[tt] += __shfl_xor(ps[tt], o);
        pd[tt] += __shfl_xor(pd[tt], o);
      }
    }
    if (grow < nrows) {
#pragma unroll
      for (int tt = 0; tt < 4; ++tt)
        h1b[(size_t)grow * 64 + tt * 16 + c] = f2b(acc[tt][r]);
      if ((c & 7) == 0) {
#pragma unroll
        for (int tt = 0; tt < 4; ++tt) {
          int head = tt * 2 + (c >> 3);
          a_src[grow * 8 + head] = ps[tt];
          a_dst[grow * 8 + head] = pd[tt];
        }
      }
    }
  }
}

// --------------------------- CSR build (bucketed, 3 kernels) -------------------
__global__ __launch_bounds__(256) void bucketA_kernel(
    const int* __restrict__ src_idx, const int* __restrict__ dst_idx,
    int* __restrict__ gcur, int* __restrict__ abuck) {
  __shared__ int hist[NBUCK];
  __shared__ int base[NBUCK];
  __shared__ int cur[NBUCK];
  int t = threadIdx.x;
  if (t < NBUCK) hist[t] = 0;
  __syncthreads();
  int e0 = blockIdx.x * CHUNKA;
  int eend = e0 + CHUNKA;
  if (eend > N_EDGES) eend = N_EDGES;
  for (int e = e0 + t; e < eend; e += 256)
    atomicAdd(&hist[(unsigned)dst_idx[e] >> 8], 1);
  __syncthreads();
  if (t < NBUCK) {
    int c = hist[t];
    base[t] = c ? atomicAdd(&gcur[t], c) : 0;
    cur[t] = 0;
  }
  __syncthreads();
  for (int e = e0 + t; e < eend; e += 256) {
    int s = src_idx[e];
    int d = dst_idx[e];
    int b = (unsigned)d >> 8;
    int r = atomicAdd(&cur[b], 1);
    abuck[b * BCAP + base[b] + r] = (s << 8) | (d & 255);
  }
}

__global__ __launch_bounds__(256) void bucket_scan_kernel(
    const int* __restrict__ gcur, int* __restrict__ bucket_base,
    int* __restrict__ indptr) {
  __shared__ int sm[256];
  int t = threadIdx.x;
  int nnodes = N_NODES - t * 256;
  if (nnodes > 256) nnodes = 256;
  if (nnodes < 0) nnodes = 0;
  int v = (t < NBUCK) ? gcur[t] + nnodes : 0;
  sm[t] = v;
  __syncthreads();
  for (int o = 1; o < 256; o <<= 1) {
    int u = (t >= o) ? sm[t - o] : 0;
    __syncthreads();
    sm[t] += u;
    __syncthreads();
  }
  if (t < NBUCK) bucket_base[t] = sm[t] - v;
  if (t == 0) indptr[N_NODES] = N_ETOT;
}

__global__ __launch_bounds__(256) void bucketB_kernel(
    const int* __restrict__ gcur, const int* __restrict__ bucket_base,
    const int* __restrict__ abuck, int* __restrict__ indptr,
    int* __restrict__ csr_src) {
  __shared__ int hist[256];
  __shared__ int sm[256];
  __shared__ int cur[256];
  int b = blockIdx.x;
  int t = threadIdx.x;
  int M = gcur[b];
  int node0 = b * 256;
  int nnodes = N_NODES - node0;
  if (nnodes > 256) nnodes = 256;
  hist[t] = (t < nnodes) ? 1 : 0;
  __syncthreads();
  const int* ab = abuck + b * BCAP;
  for (int i = t; i < M; i += 256)
    atomicAdd(&hist[ab[i] & 255], 1);
  __syncthreads();
  int v = hist[t];
  sm[t] = v;
  __syncthreads();
  for (int o = 1; o < 256; o <<= 1) {
    int u = (t >= o) ? sm[t - o] : 0;
    __syncthreads();
    sm[t] += u;
    __syncthreads();
  }
  int bbase = bucket_base[b];
  int excl = sm[t] - v;
  cur[t] = excl;
  if (t < nnodes) indptr[node0 + t] = bbase + excl;
  __syncthreads();
  for (int i = t; i < M; i += 256) {
    int entry = ab[i];
    int r = atomicAdd(&cur[entry & 255], 1);
    csr_src[bbase + r] = entry >> 8;
  }
  if (t < nnodes) {
    int r = atomicAdd(&cur[t], 1);
    csr_src[bbase + r] = node0 + t;
  }
}

// ------------- layer-1 edge softmax + aggregate ---------------------------------
__global__ __launch_bounds__(256) void agg1_kernel(
    const int* __restrict__ indptr, const int* __restrict__ csr_src,
    const unsigned short* __restrict__ h1b, const float* __restrict__ a_src1,
    const float* __restrict__ a_dst1, const float* __restrict__ bias1,
    float* __restrict__ h_elu, int n) {
  int wave = threadIdx.x >> 6;
  int lane = threadIdx.x & 63;
  int node = blockIdx.x * 4 + wave;
  if (node >= n) return;
  int j = lane >> 3;
  int h = lane & 7;
  float adst = a_dst1[(unsigned)(node * 8 + h)];
  int beg = indptr[node], end = indptr[node + 1];
  float acc0=0.f, acc1=0.f, acc2=0.f, acc3=0.f, acc4=0.f, acc5=0.f, acc6=0.f, acc7=0.f;
  float den = 0.f;
  for (int base = beg; base < end; base += 64) {
    int m = end - base;
    if (m > 64) m = 64;
    int sv = (lane < m) ? csr_src[base + lane] : 0;
    for (int p = 0; p < m; p += 8) {
      int s = __shfl(sv, p + j);
      bool act = (p + j) < m;
      float e = a_src1[(unsigned)(s * 8 + h)] + adst;
      e = (e > 0.f) ? e : 0.2f * e;
      float w = act ? __expf(e) : 0.f;
      den += w;
      u4 f = *(const u4*)(h1b + (unsigned)(s * 64 + h * 8));
      acc0 += w * b2f_lo(f.x); acc1 += w * b2f_hi(f.x);
      acc2 += w * b2f_lo(f.y); acc3 += w * b2f_hi(f.y);
      acc4 += w * b2f_lo(f.z); acc5 += w * b2f_hi(f.z);
      acc6 += w * b2f_lo(f.w); acc7 += w * b2f_hi(f.w);
    }
  }
#pragma unroll
  for (int o = 8; o < 64; o <<= 1) {
    den  += __shfl_xor(den, o);
    acc0 += __shfl_xor(acc0, o); acc1 += __shfl_xor(acc1, o);
    acc2 += __shfl_xor(acc2, o); acc3 += __shfl_xor(acc3, o);
    acc4 += __shfl_xor(acc4, o); acc5 += __shfl_xor(acc5, o);
    acc6 += __shfl_xor(acc6, o); acc7 += __shfl_xor(acc7, o);
  }
  if (j == 0) {
    float inv = 1.f / den;
    v4 b0 = *(const v4*)(bias1 + h * 8);
    v4 b1 = *(const v4*)(bias1 + h * 8 + 4);
    v4 o0, o1;
    o0[0] = acc0 * inv + b0[0]; o0[1] = acc1 * inv + b0[1];
    o0[2] = acc2 * inv + b0[2]; o0[3] = acc3 * inv + b0[3];
    o1[0] = acc4 * inv + b1[0]; o1[1] = acc5 * inv + b1[1];
    o1[2] = acc6 * inv + b1[2]; o1[3] = acc7 * inv + b1[3];
#pragma unroll
    for (int k = 0; k < 4; ++k) {
      o0[k] = (o0[k] > 0.f) ? o0[k] : expm1f(o0[k]);
      o1[k] = (o1[k] > 0.f) ? o1[k] : expm1f(o1[k]);
    }
    *(v4*)(h_elu + (size_t)node * 64 + h * 8)     = o0;
    *(v4*)(h_elu + (size_t)node * 64 + h * 8 + 4) = o1;
  }
}

// --------- GEMM2: h_elu(50000x64) @ W2(64x16) + attn2 logits epilogue ----------
__global__ __launch_bounds__(256) void gemm2_kernel(
    const float* __restrict__ h_elu, const float* __restrict__ W2,
    const float* __restrict__ att_src2, const float* __restrict__ att_dst2,
    unsigned short* __restrict__ h2b, float* __restrict__ a_src2,
    float* __restrict__ a_dst2, int n) {
  __shared__ float xs[64][68];
  __shared__ float ws[64][16];
  int t = threadIdx.x;
  int row0 = blockIdx.x * 64;
  {
    int k = t >> 2, c4 = (t & 3) * 4;
    *(v4*)&ws[k][c4] = *(const v4*)(W2 + (size_t)k * 16 + c4);
  }
#pragma unroll
  for (int r = 0; r < 4; ++r) {
    int idx = t + r * 256;
    int m = idx >> 4;
    int c4 = (idx & 15) * 4;
    v4 v = 0.f;
    int grow = row0 + m;
    if (grow < n) v = *(const v4*)(h_elu + (size_t)grow * 64 + c4);
    *(v4*)&xs[m][c4] = v;
  }
  __syncthreads();
  int r = t >> 2, q = t & 3;
  int grow = row0 + r;
  v4 acc = 0.f;
#pragma unroll
  for (int k = 0; k < 64; ++k) {
    acc += xs[r][k] * *(const v4*)&ws[k][q * 4];
  }
  v4 asv = *(const v4*)(att_src2 + q * 4);
  v4 adv = *(const v4*)(att_dst2 + q * 4);
  float ps = acc[0] * asv[0] + acc[1] * asv[1] + acc[2] * asv[2] + acc[3] * asv[3];
  float pd = acc[0] * adv[0] + acc[1] * adv[1] + acc[2] * adv[2] + acc[3] * adv[3];
  ps += __shfl_xor(ps, 1); ps += __shfl_xor(ps, 2);
  pd += __shfl_xor(pd, 1); pd += __shfl_xor(pd, 2);
  if (grow < n) {
    us4 o;
    o.x = f2b(acc[0]); o.y = f2b(acc[1]); o.z = f2b(acc[2]); o.w = f2b(acc[3]);
    *(us4*)(h2b + (size_t)grow * 16 + q * 4) = o;
    if (q == 0) { a_src2[grow] = ps; a_dst2[grow] = pd; }
  }
}

// ------- layer-2 aggregate + bias + log_softmax --------------------------------
__global__ __launch_bounds__(256) void agg2_kernel(
    const int* __restrict__ indptr, const int* __restrict__ csr_src,
    const unsigned short* __restrict__ h2b, const float* __restrict__ a_src2,
    const float* __restrict__ a_dst2, const float* __restrict__ bias2,
    float* __restrict__ out, int n) {
  int wave = threadIdx.x >> 6;
  int lane = threadIdx.x & 63;
  int node = blockIdx.x * 4 + wave;
  if (node >= n) return;
  int j = lane >> 3;
  int sub = lane & 7;
  float adst = a_dst2[node];
  int beg = indptr[node], end = indptr[node + 1];
  float acc0 = 0.f, acc1 = 0.f, den = 0.f;
  for (int base = beg; base < end; base += 64) {
    int m = end - base;
    if (m > 64) m = 64;
    int sv = (lane < m) ? csr_src[base + lane] : 0;
    for (int p = 0; p < m; p += 8) {
      int s = __shfl(sv, p + j);
      bool act = (p + j) < m;
      float e = a_src2[(unsigned)s] + adst;
      e = (e > 0.f) ? e : 0.2f * e;
      float w = act ? __expf(e) : 0.f;
      den += w;
      unsigned int f = *(const unsigned int*)(h2b + (unsigned)(s * 16 + sub * 2));
      acc0 += w * b2f_lo(f);
      acc1 += w * b2f_hi(f);
    }
  }
#pragma unroll
  for (int o = 8; o < 64; o <<= 1) {
    den  += __shfl_xor(den, o);
    acc0 += __shfl_xor(acc0, o);
    acc1 += __shfl_xor(acc1, o);
  }
  float inv = 1.f / den;
  float v0 = acc0 * inv + bias2[sub * 2];
  float v1 = acc1 * inv + bias2[sub * 2 + 1];
  float mx = fmaxf(v0, v1);
#pragma unroll
  for (int o = 1; o < 8; o <<= 1) mx = fmaxf(mx, __shfl_xor(mx, o));
  float ss = __expf(v0 - mx) + __expf(v1 - mx);
#pragma unroll
  for (int o = 1; o < 8; o <<= 1) ss += __shfl_xor(ss, o);
  float lg = mx + __logf(ss);
  if (j == 0) {
    v2 r;
    r[0] = v0 - lg;
    r[1] = v1 - lg;
    *(v2*)(out + (size_t)node * 16 + sub * 2) = r;
  }
}

// ------------------------------------------------------------------------------
extern "C" void kernel_launch(void* const* d_in, const int* in_sizes, int n_in,
                              void* d_out, int out_size, void* d_ws, size_t ws_size,
                              hipStream_t stream) {
  const float* x        = (const float*)d_in[0];
  const int*   ei       = (const int*)d_in[1];
  const float* W1       = (const float*)d_in[2];
  const float* att_src1 = (const float*)d_in[3];
  const float* att_dst1 = (const float*)d_in[4];
  const float* bias1    = (const float*)d_in[5];
  const float* W2       = (const float*)d_in[6];
  const float* att_src2 = (const float*)d_in[7];
  const float* att_dst2 = (const float*)d_in[8];
  const float* bias2    = (const float*)d_in[9];
  const int* src_idx = ei;
  const int* dst_idx = ei + N_EDGES;

  char* p = (char*)d_ws;
  auto alloc = [&](size_t bytes) {
    void* r = (void*)p;
    p += (bytes + 255) & ~(size_t)255;
    return r;
  };
  unsigned short* h1b = (unsigned short*)alloc((size_t)N_NODES * 64 * 2);
  float* h_elu   = (float*)alloc((size_t)N_NODES * 64 * 4);
  float* a_src1  = (float*)alloc((size_t)N_NODES * 8 * 4);
  float* a_dst1  = (float*)alloc((size_t)N_NODES * 8 * 4);
  unsigned short* h2b = (unsigned short*)alloc((size_t)N_NODES * 16 * 2);
  float* a_src2  = (float*)alloc((size_t)N_NODES * 4);
  float* a_dst2  = (float*)alloc((size_t)N_NODES * 4);
  int* indptr    = (int*)alloc((size_t)(N_NODES + 1) * 4);
  int* gcur      = (int*)alloc((size_t)NBUCK * 4);
  int* bucket_base = (int*)alloc((size_t)(NBUCK + 1) * 4);
  int* csr_src   = (int*)alloc((size_t)N_ETOT * 4);
  unsigned short* W1bT = (unsigned short*)alloc((size_t)64 * F_IN * 2);
  // abuck (9.6 MB) aliases h_elu (12.8 MB): build finishes before agg1 writes h_elu
  int* abuck     = (int*)h_elu;

  hipMemsetAsync(gcur, 0, (size_t)NBUCK * 4, stream);

  w1t_kernel<<<(F_IN * 64 + 255) / 256, 256, 0, stream>>>(W1, W1bT);
  gemm1_kernel<<<(N_NODES + 63) / 64, 256, 0, stream>>>(
      x, W1bT, att_src1, att_dst1, h1b, a_src1, a_dst1, N_NODES);

  bucketA_kernel<<<(N_EDGES + CHUNKA - 1) / CHUNKA, 256, 0, stream>>>(
      src_idx, dst_idx, gcur, abuck);
  bucket_scan_kernel<<<1, 256, 0, stream>>>(gcur, bucket_base, indptr);
  bucketB_kernel<<<NBUCK, 256, 0, stream>>>(
      gcur, bucket_base, abuck, indptr, csr_src);

  agg1_kernel<<<N_NODES / 4, 256, 0, stream>>>(
      indptr, csr_src, h1b, a_src1, a_dst1, bias1, h_elu, N_NODES);

  gemm2_kernel<<<(N_NODES + 63) / 64, 256, 0, stream>>>(
      h_elu, W2, att_src2, att_dst2, h2b, a_src2, a_dst2, N_NODES);

  agg2_kernel<<<N_NODES / 4, 256, 0, stream>>>(
      indptr, csr_src, h2b, a_src2, a_dst2, bias2, (float*)d_out, N_NODES);
}